// Round 1
// baseline (358.261 us; speedup 1.0000x reference)
//
#include <hip/hip_runtime.h>

#define N   160
#define SZl 1
#define SYl 160
#define SXl (160*160)

__global__ __launch_bounds__(640) void piano_energy_kernel(
    const float* __restrict__ C,   const float* __restrict__ Vx,
    const float* __restrict__ Vy,  const float* __restrict__ Vz,
    const float* __restrict__ Dxx, const float* __restrict__ Dxy,
    const float* __restrict__ Dxz, const float* __restrict__ Dyy,
    const float* __restrict__ Dyz, const float* __restrict__ Dzz,
    float* __restrict__ out)
{
    const int z = threadIdx.x;                       // 0..159 (contiguous axis)
    const int y = blockIdx.y * 4 + threadIdx.y;      // 0..159
    const int x = blockIdx.x;                        // 0..159 (block-uniform)
    const int b = blockIdx.z;                        // 0..1

    const int idx = ((b * N + x) * N + y) * N + z;

    // ---- clamped neighbor offsets (never fault; reproduce boundary rules) ----
    const int oxp = (x < N - 1) ?  SXl : 0;
    const int oxm = (x > 0)     ? -SXl : 0;
    const int oyp = (y < N - 1) ?  SYl : 0;
    const int oym = (y > 0)     ? -SYl : 0;
    const int ozp = (z < N - 1) ?  SZl : 0;
    const int ozm = (z > 0)     ? -SZl : 0;

    // central-diff scale: 0.5 interior, 1.0 at either boundary (one-sided)
    const float sx = (x == 0 || x == N - 1) ? 1.f : 0.5f;
    const float sy = (y == 0 || y == N - 1) ? 1.f : 0.5f;
    const float sz = (z == 0 || z == N - 1) ? 1.f : 0.5f;

    // ---- C face neighborhood (7 loads) ----
    const float c0  = C[idx];
    const float cxp = C[idx + oxp], cxm = C[idx + oxm];
    const float cyp = C[idx + oyp], cym = C[idx + oym];
    const float czp = C[idx + ozp], czm = C[idx + ozm];

    // first derivatives of C
    const float Cx_c = sx * (cxp - cxm);
    const float Cy_c = sy * (cyp - cym);
    const float Cz_c = sz * (czp - czm);
    const float Cx_f = (x < N - 1) ? (cxp - c0) : (c0 - cxm);
    const float Cy_f = (y < N - 1) ? (cyp - c0) : (c0 - cym);
    const float Cz_f = (z < N - 1) ? (czp - c0) : (c0 - czm);
    const float Cx_b = (x > 0) ? (c0 - cxm) : (cxp - c0);
    const float Cy_b = (y > 0) ? (c0 - cym) : (cyp - c0);
    const float Cz_b = (z > 0) ? (c0 - czm) : (czp - c0);

    // pure second derivatives  dAb(CA_f): interior = laplacian stencil,
    // coord==0 copies value at 1, coord==N-1 is exactly 0.
    float sXX, sYY, sZZ;
    if (x == 0)          sXX = C[idx + 2 * SXl] - 2.f * cxp + c0;
    else if (x == N - 1) sXX = 0.f;
    else                 sXX = cxp - 2.f * c0 + cxm;
    if (y == 0)          sYY = C[idx + 2 * SYl] - 2.f * cyp + c0;
    else if (y == N - 1) sYY = 0.f;
    else                 sYY = cyp - 2.f * c0 + cym;
    if (z == 0)          sZZ = C[idx + 2 * SZl] - 2.f * czp + c0;
    else if (z == N - 1) sZZ = 0.f;
    else                 sZZ = czp - 2.f * c0 + czm;

    // ---- cross second derivatives dAb(CB_f), generic clamped-offset form ----
    // forward-B offsets
    const int ofxp = oxp;                       const int ofx0 = (x == N - 1) ? -SXl : 0;
    const int ofyp = oyp;                       const int ofy0 = (y == N - 1) ? -SYl : 0;
    const int ofzp = ozp;                       const int ofz0 = (z == N - 1) ? -SZl : 0;
    // backward-A positions (a'=max(a,1)): pair (a', a'-1)
    const int obx1 = (x > 0) ? 0 : SXl;         const int obx0 = obx1 - SXl;
    const int oby1 = (y > 0) ? 0 : SYl;         const int oby0 = oby1 - SYl;
    const int obz1 = (z > 0) ? 0 : SZl;         const int obz0 = obz1 - SZl;

    const float crossXY = (C[idx + obx1 + ofyp] - C[idx + obx1 + ofy0])
                        - (C[idx + obx0 + ofyp] - C[idx + obx0 + ofy0]);
    const float crossYX = (C[idx + oby1 + ofxp] - C[idx + oby1 + ofx0])
                        - (C[idx + oby0 + ofxp] - C[idx + oby0 + ofx0]);
    const float crossYZ = (C[idx + oby1 + ofzp] - C[idx + oby1 + ofz0])
                        - (C[idx + oby0 + ofzp] - C[idx + oby0 + ofz0]);
    const float crossZY = (C[idx + obz1 + ofyp] - C[idx + obz1 + ofy0])
                        - (C[idx + obz0 + ofyp] - C[idx + obz0 + ofy0]);
    const float crossZX = (C[idx + obz1 + ofxp] - C[idx + obz1 + ofx0])
                        - (C[idx + obz0 + ofxp] - C[idx + obz0 + ofx0]);
    const float crossXZ = (C[idx + obx1 + ofzp] - C[idx + obx1 + ofz0])
                        - (C[idx + obx0 + ofzp] - C[idx + obx0 + ofz0]);

    // ---- diffusion-tensor divergence terms (central diffs of D) ----
    const float dDxx_x = sx * (Dxx[idx + oxp] - Dxx[idx + oxm]);
    const float dDxy_x = sx * (Dxy[idx + oxp] - Dxy[idx + oxm]);
    const float dDxy_y = sy * (Dxy[idx + oyp] - Dxy[idx + oym]);
    const float dDxz_x = sx * (Dxz[idx + oxp] - Dxz[idx + oxm]);
    const float dDxz_z = sz * (Dxz[idx + ozp] - Dxz[idx + ozm]);
    const float dDyy_y = sy * (Dyy[idx + oyp] - Dyy[idx + oym]);
    const float dDyz_y = sy * (Dyz[idx + oyp] - Dyz[idx + oym]);
    const float dDyz_z = sz * (Dyz[idx + ozp] - Dyz[idx + ozm]);
    const float dDzz_z = sz * (Dzz[idx + ozp] - Dzz[idx + ozm]);

    const float t1 = dDxx_x + dDxy_y + dDxz_z;
    const float t2 = dDxy_x + dDyy_y + dDyz_z;
    const float t3 = dDxz_x + dDyz_y + dDzz_z;

    const float Dxx0 = Dxx[idx], Dyy0 = Dyy[idx], Dzz0 = Dzz[idx];
    const float Dxy0 = Dxy[idx], Dyz0 = Dyz[idx], Dxz0 = Dxz[idx];

    const float diff = t1 * Cx_c + t2 * Cy_c + t3 * Cz_c
                     + Dxx0 * sXX + Dyy0 * sYY + Dzz0 * sZZ
                     + Dxy0 * (crossXY + crossYX)
                     + Dyz0 * (crossYZ + crossZY)
                     + Dxz0 * (crossZX + crossXZ);

    // ---- advection (upwind) ----
    const float Vx0 = Vx[idx], Vy0 = Vy[idx], Vz0 = Vz[idx];
    const float dVx = sx * (Vx[idx + oxp] - Vx[idx + oxm]);
    const float dVy = sy * (Vy[idx + oyp] - Vy[idx + oym]);
    const float dVz = sz * (Vz[idx + ozp] - Vz[idx + ozm]);

    const float C_x = (Vx0 > 0.f) ? Cx_b : Cx_f;
    const float C_y = (Vy0 > 0.f) ? Cy_b : Cy_f;
    const float C_z = (Vz0 > 0.f) ? Cz_b : Cz_f;

    const float adv = -(Vx0 * C_x + Vy0 * C_y + Vz0 * C_z)
                    - c0 * (dVx + dVy + dVz);

    out[idx] = diff + adv;
}

extern "C" void kernel_launch(void* const* d_in, const int* in_sizes, int n_in,
                              void* d_out, int out_size, void* d_ws, size_t ws_size,
                              hipStream_t stream) {
    const float* C   = (const float*)d_in[0];
    const float* Vx  = (const float*)d_in[1];
    const float* Vy  = (const float*)d_in[2];
    const float* Vz  = (const float*)d_in[3];
    const float* Dxx = (const float*)d_in[4];
    const float* Dxy = (const float*)d_in[5];
    const float* Dxz = (const float*)d_in[6];
    const float* Dyy = (const float*)d_in[7];
    const float* Dyz = (const float*)d_in[8];
    const float* Dzz = (const float*)d_in[9];
    float* out = (float*)d_out;

    dim3 grid(N, N / 4, 2);
    dim3 block(N, 4, 1);
    hipLaunchKernelGGL(piano_energy_kernel, grid, block, 0, stream,
                       C, Vx, Vy, Vz, Dxx, Dxy, Dxz, Dyy, Dyz, Dzz, out);
}